// Round 10
// baseline (1797.604 us; speedup 1.0000x reference)
//
#include <hip/hip_runtime.h>
#include <hip/hip_bf16.h>

namespace {

constexpr int D    = 512;
constexpr int S    = 1536;
constexpr int N    = S + 1;      // 1537
constexpr int L    = 4;
constexpr int H    = 4;
constexpr int R    = 32;
constexpr int W    = 128;
constexpr int HFF  = 1024;
constexpr float EPS = 1e-5f;

constexpr int TB   = 4;
constexpr int NB4  = (N + TB - 1) / TB;   // 385 virtual blocks
constexpr int SP   = 133;
constexpr int SPAD = 136;

constexpr int MT32  = (N + 31) / 32;        // 49
constexpr int NVQK  = (256 / 32) * MT32;    // 392
constexpr int NVF1  = (HFF / 32) * MT32;    // 1568
constexpr int NVF2  = (D / 32) * MT32;      // 784
constexpr int NVPK  = L * 512;              // 2048
constexpr int NVT1  = (HFF/32)*(D/32)*L;    // 2048
constexpr int NVT2  = (D/32)*(HFF/32)*L;    // 2048
constexpr int NVPREP = NVPK + NVT1 + NVT2 + N;   // 7681

constexpr int GRID = 512;   // == guaranteed capacity: __launch_bounds__(256,2)
                            // + 48KB LDS -> >=2 blocks/CU x 256 CUs

typedef __attribute__((ext_vector_type(8))) short short8;
typedef __attribute__((ext_vector_type(4))) float floatx4;

struct Params {
  const int* ids; const float* emb; const float* pos;
  const float* ln_in_g; const float* ln_in_b;
  const float* anchor_state; const float* anchor_val;
  const float* state_w; const float* state_b;
  const float* wq; const float* wk; const float* gate;
  const float* ln_g; const float* ln_b;
  const float* ffn_w1; const float* ffn_b1;
  const float* ffn_w2; const float* ffn_b2;
  const float* ln2_g; const float* ln2_b;
  float* out;
  float* val0; float* val1;
  ushort* val0bf; ushort* x2bf; ushort* hbf; ushort* qkbf;
  ushort* wqkbf; ushort* w1t; ushort* w2t;
  float* st0; float* st1;
  unsigned int* bar;
};

__device__ inline ushort f2bf(float x){
  __hip_bfloat16 h = __float2bfloat16(x);
  return *reinterpret_cast<ushort*>(&h);
}
__device__ inline float bf2f(uint u){
  union { uint u; float f; } c; c.u = u << 16; return c.f;
}

__device__ inline float wave_sum(float v){
#pragma unroll
  for (int o = 32; o; o >>= 1) v += __shfl_xor(v, o, 64);
  return v;
}
__device__ inline float wave_max(float v){
#pragma unroll
  for (int o = 32; o; o >>= 1) v = fmaxf(v, __shfl_xor(v, o, 64));
  return v;
}
__device__ inline float block_sum(float v, float* scr){
  v = wave_sum(v);
  __syncthreads();
  if ((threadIdx.x & 63) == 0) scr[threadIdx.x >> 6] = v;
  __syncthreads();
  return scr[0] + scr[1] + scr[2] + scr[3];
}

// software grid barrier: arrive (device-scope atomic) + spin to generation
// target. Safe: all GRID blocks are co-resident (grid == min-occupancy
// capacity) and no block retires before the last barrier.
__device__ inline void gbar(unsigned int* cnt, unsigned int target){
  __syncthreads();
  if (threadIdx.x == 0){
    __threadfence();   // prior writes visible device-wide
    __hip_atomic_fetch_add(cnt, 1u, __ATOMIC_ACQ_REL, __HIP_MEMORY_SCOPE_AGENT);
    while (__hip_atomic_load(cnt, __ATOMIC_ACQUIRE, __HIP_MEMORY_SCOPE_AGENT) < target)
      __builtin_amdgcn_s_sleep(2);
    __threadfence();
  }
  __syncthreads();
}

__device__ void pack_stage(int vb, const Params& p){
  int i = vb * 256 + threadIdx.x;
  int d = i & 511;
  int c = (i >> 9) & 255;
  int l = i >> 17;
  int cc = c & 127;
  int h = cc >> 5, r = cc & 31;
  const float* src = (c < 128) ? p.wq : p.wk;
  p.wqkbf[i] = f2bf(src[((l * H + h) * D + d) * R + r]);
}

__device__ void transpose_stage(int vb, char* smem, const float* src0,
                                ushort* dst0, int rows, int cols){
  float (*tile)[33] = (float(*)[33])smem;
  int ctiles = cols / 32, rtiles = rows / 32;
  int cx = vb % ctiles;
  int ry = (vb / ctiles) % rtiles;
  int z  = vb / (ctiles * rtiles);
  const float* s = src0 + (size_t)z * rows * cols;
  ushort* d = dst0 + (size_t)z * rows * cols;
  int c0 = cx * 32, r0 = ry * 32;
  int tx = threadIdx.x & 31, ty = threadIdx.x >> 5;
  for (int rr = ty; rr < 32; rr += 8)
    tile[rr][tx] = s[(size_t)(r0 + rr) * cols + c0 + tx];
  __syncthreads();
  for (int rr = ty; rr < 32; rr += 8)
    d[(size_t)(c0 + rr) * rows + r0 + tx] = f2bf(tile[tx][rr]);
}

__device__ void embed_stage(int n, char* smem, const Params& p){
  float* scr = (float*)smem;
  int t = threadIdx.x;
  if (n == 0){
    float a0 = p.anchor_val[t], a1 = p.anchor_val[t + 256];
    p.val0[t] = a0; p.val0[t + 256] = a1;
    p.val0bf[t] = f2bf(a0); p.val0bf[t + 256] = f2bf(a1);
    if (t == 0) p.st0[0] = p.anchor_state[0];
    return;
  }
  int tp = n - 1;
  int id = p.ids[tp];
  float x0 = p.emb[(size_t)id * D + t]       + p.pos[tp * D + t];
  float x1 = p.emb[(size_t)id * D + t + 256] + p.pos[tp * D + t + 256];
  float mean = block_sum(x0 + x1, scr) * (1.f / D);
  float var  = block_sum(x0 * x0 + x1 * x1, scr) * (1.f / D) - mean * mean;
  float rs   = rsqrtf(var + EPS);
  float y0 = (x0 - mean) * rs * p.ln_in_g[t]       + p.ln_in_b[t];
  float y1 = (x1 - mean) * rs * p.ln_in_g[t + 256] + p.ln_in_b[t + 256];
  p.val0[n * D + t]       = y0;
  p.val0[n * D + t + 256] = y1;
  p.val0bf[n * D + t]       = f2bf(y0);
  p.val0bf[n * D + t + 256] = f2bf(y1);
  float ts = block_sum(y0 * p.state_w[t] + y1 * p.state_w[t + 256], scr);
  if (t == 0) p.st0[n] = ts + p.state_b[0];
}

template<int ACT>
__device__ void gemm_stage(int bx, int by, char* smem,
                           const ushort* __restrict__ A,
                           const ushort* __restrict__ Bt,
                           const float* __restrict__ bias,
                           const float* __restrict__ resid,
                           float* __restrict__ C, ushort* __restrict__ Cbf,
                           int M, int Kd, int Nc)
{
  constexpr int SLAB = 272;
  ushort* As = (ushort*)smem;
  ushort* Bs = (ushort*)(smem + 8 * SLAB * 2);
  int row0 = by * 32;
  int col0 = bx * 32;
  int t = threadIdx.x;
  int lane = t & 63, w = t >> 6;
  int wr = w & 1, wc = w >> 1;
  int q = lane >> 4, lm = lane & 15;

  int srow = t >> 3, skb = t & 7;
  int arow = min(row0 + srow, M - 1);
  const ushort* ag = A  + (size_t)arow * Kd + skb * 8;
  const ushort* bg = Bt + (size_t)(col0 + srow) * Kd + skb * 8;
  ushort* as = &As[skb * SLAB + srow * 8];
  ushort* bs = &Bs[skb * SLAB + srow * 8];

  const ushort* ar = &As[(wr * 16 + lm) * 8];
  const ushort* br = &Bs[(wc * 16 + lm) * 8];

  floatx4 acc = {0.f, 0.f, 0.f, 0.f};

  for (int k0 = 0; k0 < Kd; k0 += 64){
    uint4 av = *(const uint4*)(ag + k0);
    uint4 bv = *(const uint4*)(bg + k0);
    *(uint4*)as = av;
    *(uint4*)bs = bv;
    __syncthreads();
#pragma unroll
    for (int kk = 0; kk < 2; ++kk){
      short8 a = *(const short8*)(ar + (kk * 4 + q) * SLAB);
      short8 b = *(const short8*)(br + (kk * 4 + q) * SLAB);
      acc = __builtin_amdgcn_mfma_f32_16x16x32_bf16(a, b, acc, 0, 0, 0);
    }
    __syncthreads();
  }

  int col = col0 + wc * 16 + lm;
#pragma unroll
  for (int r = 0; r < 4; ++r){
    int row = row0 + wr * 16 + q * 4 + r;
    if (row >= M) continue;
    float v = acc[r] + (bias ? bias[col] : 0.f);
    if (ACT == 1) v = 0.5f * v * (1.f + erff(v * 0.70710678118654752f));
    if (resid) v += resid[(size_t)row * Nc + col];
    size_t o = (size_t)row * Nc + col;
    if (C)   C[o] = v;
    if (Cbf) Cbf[o] = f2bf(v);
  }
}

__device__ void attn_stage(int vb, char* smem, const Params& p,
                           const float* __restrict__ state_in,
                           float* __restrict__ state_out,
                           const float* __restrict__ gate_p,
                           const float* __restrict__ lng,
                           const float* __restrict__ lnb,
                           const float* __restrict__ ln2g,
                           const float* __restrict__ ln2b)
{
  float* kg  = (float*)smem;
  float* qsh = (float*)(smem + 34816);
  float* ssh = (float*)(smem + 36864);
  float* ash = (float*)(smem + 45568);
  const ushort* qkbf = p.qkbf;
  const int n0 = vb * TB;
  const int t = threadIdx.x;
  const int w = t >> 6, l = t & 63;
  const float gate = gate_p[0];
  const float scale = 0.17677669529663687f;

#pragma unroll
  for (int i = t; i < TB * 128; i += 256){
    int it = i >> 7, ch = i & 127;
    int gr = min(n0 + it, N - 1);
    qsh[i] = bf2f((uint)qkbf[(size_t)gr * 256 + ch]);
  }

  for (int half = 0; half < 2; ++half){
    for (int i = t; i < SP * 16; i += 256){
      int c = i >> 4, c4 = i & 15;
      int g = (c == 132) ? 0 : min(max(n0 - W + c, 0), N - 1);
      uint2 v = *(const uint2*)&qkbf[(size_t)g * 256 + 128 + half * 64 + c4 * 4];
      int ch = c4 * 4;
      kg[(ch + 0) * SPAD + c] = bf2f(v.x & 0xffffu);
      kg[(ch + 1) * SPAD + c] = bf2f(v.x >> 16);
      kg[(ch + 2) * SPAD + c] = bf2f(v.y & 0xffffu);
      kg[(ch + 3) * SPAD + c] = bf2f(v.y >> 16);
    }
    __syncthreads();
    for (int tk = t; tk < TB * 2 * SP; tk += 256){
      int c = tk % SP;
      int th = tk / SP;
      int tok = th & 3, hh = th >> 2;
      int h = half * 2 + hh;
      const float* qs = &qsh[tok * 128 + h * 32];
      const float* ks = &kg[hh * 32 * SPAD + c];
      float acc = 0.f;
#pragma unroll
      for (int r = 0; r < 32; ++r) acc += qs[r] * ks[r * SPAD];
      ssh[(tok * 4 + h) * SPAD + c] = acc * scale;
    }
    __syncthreads();
  }

  for (int i = t; i < TB * SP; i += 256){
    int tok = i / SP, c = i - tok * SP;
    const float* sr = &ssh[tok * 4 * SPAD + c];
    float s0 = sr[0], s1 = sr[SPAD], s2 = sr[2 * SPAD], s3 = sr[3 * SPAD];
    float a0 = fabsf(s0), a1 = fabsf(s1), a2 = fabsf(s2), a3 = fabsf(s3);
    float m = fmaxf(fmaxf(a0, a1), fmaxf(a2, a3));
    float w0 = expf(a0 - m), w1 = expf(a1 - m), w2 = expf(a2 - m), w3 = expf(a3 - m);
    ash[tok * SPAD + c] = (s0 * w0 + s1 * w1 + s2 * w2 + s3 * w3) / (w0 + w1 + w2 + w3);
  }
  __syncthreads();

  {
    const int n = n0 + w;
    float* arow = &ash[w * SPAD];
    float a0 = arow[l];
    float a1 = arow[64 + l];
    float a2 = (l < 5) ? arow[128 + l] : 0.f;
    bool ok0 = (l >= w) && (n0 - W + l >= 0);
    bool ok1 = (n0 - W + 64 + l >= 0);
    bool ok2;
    if (l < 4)       ok2 = (l <= w);
    else if (l == 4) ok2 = (n > W);
    else             ok2 = false;
    float cand = -3.4e38f;
    if (ok0) cand = fabsf(a0);
    if (ok1) cand = fmaxf(cand, fabsf(a1));
    if (ok2) cand = fmaxf(cand, fabsf(a2));
    float m = wave_max(cand);
    float e0 = ok0 ? expf(fabsf(a0) - m) : 0.f;
    float e1 = ok1 ? expf(fabsf(a1) - m) : 0.f;
    float e2 = ok2 ? expf(fabsf(a2) - m) : 0.f;
    float inv = 1.f / wave_sum(e0 + e1 + e2);
    int g0 = min(max(n0 - W + l, 0), N - 1);
    int g1 = min(max(n0 - W + 64 + l, 0), N - 1);
    int g2 = (l < 4) ? min(n0 + l, N - 1) : 0;
    float sg0 = (a0 > 0.f) ? 1.f : ((a0 < 0.f) ? -1.f : 0.f);
    float sg1 = (a1 > 0.f) ? 1.f : ((a1 < 0.f) ? -1.f : 0.f);
    float sg2 = (a2 > 0.f) ? 1.f : ((a2 < 0.f) ? -1.f : 0.f);
    float t0 = sg0 * e0 * inv * state_in[g0];
    float t1 = sg1 * e1 * inv * state_in[g1];
    float t2 = (l < 5) ? sg2 * e2 * inv * state_in[g2] : 0.f;
    arow[l] = t0;
    arow[64 + l] = t1;
    if (l < 5) arow[128 + l] = t2;
    float ds = wave_sum(t0 + t1 + t2);
    if (l == 0 && n < N) state_out[n] = state_in[n] + gate * ds;
  }
  __syncthreads();

  float acc[TB][2];
#pragma unroll
  for (int k = 0; k < TB; ++k){ acc[k][0] = 0.f; acc[k][1] = 0.f; }
  {
    const int d0 = 2 * t;
    for (int c = 0; c < SP; ++c){
      int g = (c == 132) ? 0 : min(max(n0 - W + c, 0), N - 1);
      uint v = *(const uint*)&p.val0bf[(size_t)g * D + d0];
      float vx = bf2f(v & 0xffffu), vy = bf2f(v >> 16);
#pragma unroll
      for (int k = 0; k < TB; ++k){
        float e = ash[k * SPAD + c];
        acc[k][0] += e * vx;
        acc[k][1] += e * vy;
      }
    }
  }
  float* xbuf = kg;
  {
    const int d0 = 2 * t;
#pragma unroll
    for (int k = 0; k < TB; ++k){
      int nc = min(n0 + k, N - 1);
      float2 vv = *(const float2*)&p.val0[(size_t)nc * D + d0];
      xbuf[k * 520 + d0]     = vv.x + gate * acc[k][0];
      xbuf[k * 520 + d0 + 1] = vv.y + gate * acc[k][1];
    }
  }
  __syncthreads();

  {
    const int n = n0 + w;
    const int d = l * 8;
    const float* xr = &xbuf[w * 520 + d];
    float x[8];
#pragma unroll
    for (int j = 0; j < 8; ++j) x[j] = xr[j];
    float s1 = 0.f, s2 = 0.f;
#pragma unroll
    for (int j = 0; j < 8; ++j){ s1 += x[j]; s2 += x[j] * x[j]; }
    s1 = wave_sum(s1); s2 = wave_sum(s2);
    float mean = s1 * (1.f / D);
    float var  = s2 * (1.f / D) - mean * mean;
    float rs   = rsqrtf(var + EPS);
    float y[8];
    float u1 = 0.f, u2 = 0.f;
#pragma unroll
    for (int j = 0; j < 8; ++j){
      float yv = (x[j] - mean) * rs * lng[d + j] + lnb[d + j];
      y[j] = yv; u1 += yv; u2 += yv * yv;
    }
    u1 = wave_sum(u1); u2 = wave_sum(u2);
    float mean2 = u1 * (1.f / D);
    float var2  = u2 * (1.f / D) - mean2 * mean2;
    float rs2   = rsqrtf(var2 + EPS);
    if (n < N){
      *(float4*)&p.val1[(size_t)n * D + d]     = make_float4(y[0], y[1], y[2], y[3]);
      *(float4*)&p.val1[(size_t)n * D + d + 4] = make_float4(y[4], y[5], y[6], y[7]);
      uint4 pk;
      uint z0 = f2bf((y[0] - mean2) * rs2 * ln2g[d + 0] + ln2b[d + 0]);
      uint z1 = f2bf((y[1] - mean2) * rs2 * ln2g[d + 1] + ln2b[d + 1]);
      uint z2 = f2bf((y[2] - mean2) * rs2 * ln2g[d + 2] + ln2b[d + 2]);
      uint z3 = f2bf((y[3] - mean2) * rs2 * ln2g[d + 3] + ln2b[d + 3]);
      uint z4 = f2bf((y[4] - mean2) * rs2 * ln2g[d + 4] + ln2b[d + 4]);
      uint z5 = f2bf((y[5] - mean2) * rs2 * ln2g[d + 5] + ln2b[d + 5]);
      uint z6 = f2bf((y[6] - mean2) * rs2 * ln2g[d + 6] + ln2b[d + 6]);
      uint z7 = f2bf((y[7] - mean2) * rs2 * ln2g[d + 7] + ln2b[d + 7]);
      pk.x = z0 | (z1 << 16); pk.y = z2 | (z3 << 16);
      pk.z = z4 | (z5 << 16); pk.w = z6 | (z7 << 16);
      *(uint4*)&p.x2bf[(size_t)n * D + d] = pk;
    }
  }
}

__global__ __launch_bounds__(256, 2) void fused_all(Params p)
{
  __shared__ __align__(16) char smem[48000];
  const int bid = blockIdx.x, nB = gridDim.x;
  unsigned int gen = 0;

  for (int vb = bid; vb < NVPREP; vb += nB){
    if (vb < NVPK)                      pack_stage(vb, p);
    else if (vb < NVPK + NVT1)          transpose_stage(vb - NVPK, smem, p.ffn_w1, p.w1t, D, HFF);
    else if (vb < NVPK + NVT1 + NVT2)   transpose_stage(vb - NVPK - NVT1, smem, p.ffn_w2, p.w2t, HFF, D);
    else                                embed_stage(vb - NVPK - NVT1 - NVT2, smem, p);
    __syncthreads();
  }
  gbar(p.bar, (++gen) * GRID);

  for (int ly = 0; ly < L; ++ly){
    const float* sin_  = (ly & 1) ? p.st1 : p.st0;
    float*       sout_ = (ly & 1) ? p.st0 : p.st1;
    const ushort* wqk = p.wqkbf + (size_t)ly * 256 * D;

    for (int vb = bid; vb < NVQK; vb += nB){
      gemm_stage<0>(vb % 8, vb / 8, smem, p.val0bf, wqk,
                    nullptr, nullptr, nullptr, p.qkbf, N, D, 256);
      __syncthreads();
    }
    gbar(p.bar, (++gen) * GRID);

    for (int vb = bid; vb < NB4; vb += nB){
      attn_stage(vb, smem, p, sin_, sout_, p.gate + ly,
                 p.ln_g + ly * D, p.ln_b + ly * D,
                 p.ln2_g + ly * D, p.ln2_b + ly * D);
      __syncthreads();
    }
    gbar(p.bar, (++gen) * GRID);

    for (int vb = bid; vb < NVF1; vb += nB){
      gemm_stage<1>(vb % 32, vb / 32, smem, p.x2bf,
                    p.w1t + (size_t)ly * HFF * D, p.ffn_b1 + ly * HFF,
                    nullptr, nullptr, p.hbf, N, D, HFF);
      __syncthreads();
    }
    gbar(p.bar, (++gen) * GRID);

    float* dst = (ly == L - 1) ? p.out : p.val0;
    for (int vb = bid; vb < NVF2; vb += nB){
      gemm_stage<0>(vb % 16, vb / 16, smem, p.hbf,
                    p.w2t + (size_t)ly * HFF * D, p.ffn_b2 + ly * D,
                    p.val1, dst, p.val0bf, N, HFF, D);
      __syncthreads();
    }
    gbar(p.bar, (++gen) * GRID);
  }
}

} // anonymous namespace

extern "C" void kernel_launch(void* const* d_in, const int* in_sizes, int n_in,
                              void* d_out, int out_size, void* d_ws, size_t ws_size,
                              hipStream_t stream)
{
  (void)in_sizes; (void)n_in; (void)out_size; (void)ws_size;
  Params p;
  p.ids          = (const int*)d_in[0];
  p.emb          = (const float*)d_in[1];
  p.pos          = (const float*)d_in[2];
  p.ln_in_g      = (const float*)d_in[3];
  p.ln_in_b      = (const float*)d_in[4];
  p.anchor_state = (const float*)d_in[5];
  p.anchor_val   = (const float*)d_in[6];
  p.state_w      = (const float*)d_in[7];
  p.state_b      = (const float*)d_in[8];
  p.wq           = (const float*)d_in[9];
  p.wk           = (const float*)d_in[10];
  p.gate         = (const float*)d_in[11];
  p.ln_g         = (const float*)d_in[12];
  p.ln_b         = (const float*)d_in[13];
  p.ffn_w1       = (const float*)d_in[14];
  p.ffn_b1       = (const float*)d_in[15];
  p.ffn_w2       = (const float*)d_in[16];
  p.ffn_b2       = (const float*)d_in[17];
  p.ln2_g        = (const float*)d_in[18];
  p.ln2_b        = (const float*)d_in[19];
  p.out          = (float*)d_out;

  float* wsf  = (float*)d_ws;
  p.val0 = wsf;  wsf += (size_t)N * D;
  p.val1 = wsf;  wsf += (size_t)N * D;
  ushort* wsu = (ushort*)wsf;
  p.val0bf = wsu;  wsu += (size_t)N * D;
  p.x2bf   = wsu;  wsu += (size_t)N * D;
  p.hbf    = wsu;  wsu += (size_t)N * HFF;
  p.qkbf   = wsu;  wsu += (size_t)N * 256;
  p.wqkbf  = wsu;  wsu += (size_t)L * 256 * D;
  p.w1t    = wsu;  wsu += (size_t)L * HFF * D;
  p.w2t    = wsu;  wsu += (size_t)L * HFF * D;
  p.st0 = (float*)wsu;
  p.st1 = p.st0 + N;
  p.bar = (unsigned int*)(p.st1 + N);

  // zero the grid-barrier counter (ws is poisoned 0xAA before every launch)
  hipMemsetAsync((void*)p.bar, 0, sizeof(unsigned int), stream);
  fused_all<<<GRID, 256, 0, stream>>>(p);
}